// Round 2
// baseline (1270.907 us; speedup 1.0000x reference)
//
#include <hip/hip_runtime.h>

// ---------------------------------------------------------------------------
// SAGE-LSTM on MI355X.
// Strategy: Xpre = x@Wih^T + b precomputed once per layer (hoists the input
// GEMM out of the 16-step recurrence). LSTM kernel computes gates^T = Whh.h^T
// with MFMA 16x16x32 bf16: A = Whh (LDS, fragment-packed, prescaled by
// log2e/2log2e), B = h (LDS round-trip, stride 136 = 2-way-bank-free),
// C-layout rows = gate index -> Xpre gather is a contiguous float4 load.
// c-state fp32 in registers. 250 blocks x 5 waves x 16 nodes = 20000 exact.
//
// R1 post-mortem: absmax 0.18 was out2's dot loop covering only 8/16 uint4
// chunks (features 0-63 of 128) -> missing half of both final dot products.
// Fixed (q<16). Also upgraded Xpre to fp32 storage for precision margin.
// ---------------------------------------------------------------------------

#define NN   20000
#define L2E  1.4426950408889634f

typedef unsigned short u16;
typedef __attribute__((ext_vector_type(8))) short frag8;   // 8 x bf16
typedef __attribute__((ext_vector_type(4))) float facc4;   // 4 x f32 acc

// ---- workspace layout (bytes), total 56,914,432 ----
#define OFF_X16   0u
#define OFF_H1    5120000u
#define OFF_HN    10240000u
#define OFF_WIH1P 15360000u
#define OFF_WHH1P 15491072u
#define OFF_WIH2P 15622144u
#define OFF_WHH2P 15753216u
#define OFF_WS1P  15884288u
#define OFF_WN1P  15917056u
#define OFF_WS2B  15949824u
#define OFF_WN2B  15950080u
#define OFF_B1    15950336u
#define OFF_B2    15952384u
#define OFF_XPRE  15954432u   // fp32 [NN,512] = 40,960,000 B

__device__ __forceinline__ u16 f2bf(float f) {
  union { float f; unsigned u; } v; v.f = f;
  unsigned r = (v.u + 0x7fffu + ((v.u >> 16) & 1u)) >> 16;  // RNE
  return (u16)r;
}
__device__ __forceinline__ float bflo(unsigned u) {
  union { unsigned u; float f; } v; v.u = u << 16; return v.f;
}
__device__ __forceinline__ float bfhi(unsigned u) {
  union { unsigned u; float f; } v; v.u = u & 0xffff0000u; return v.f;
}
__device__ __forceinline__ facc4 mfma16(frag8 a, frag8 b, facc4 c) {
  return __builtin_amdgcn_mfma_f32_16x16x32_bf16(a, b, c, 0, 0, 0);
}
// x prescaled by L2E: sigmoid(x) = 1/(1+2^-xp)
__device__ __forceinline__ float sigm_ps(float xp) {
  return __builtin_amdgcn_rcpf(1.f + __builtin_amdgcn_exp2f(-xp));
}
// x prescaled by 2*L2E: tanh(x) = 1 - 2/(1+2^xp)
__device__ __forceinline__ float tanh_ps(float xp) {
  return 1.f - 2.f * __builtin_amdgcn_rcpf(1.f + __builtin_amdgcn_exp2f(xp));
}
__device__ __forceinline__ float gate_scale(int row) {
  return (row >= 256 && row < 384) ? 2.f * L2E : L2E;  // g-gate rows get 2*log2e
}

// pack [R,128] fp32 row-major -> A-fragment order: dst[i] where
// i = ((tj*4+kb)*64 + lane)*8 + e ; A[row = tj*16+(lane&15)][k = kb*32+(lane>>4)*8+e]
__device__ __forceinline__ void pack512(u16* dst, const float* src, int i) {
  int e = i & 7, ln = (i >> 3) & 63, kb = (i >> 9) & 3, tj = i >> 11;
  int row = tj * 16 + (ln & 15);
  int col = kb * 32 + (ln >> 4) * 8 + e;
  dst[i] = f2bf(src[row * 128 + col] * gate_scale(row));
}
__device__ __forceinline__ void pack128(u16* dst, const float* src, int i) {
  int e = i & 7, ln = (i >> 3) & 63, kb = (i >> 9) & 3, tj = i >> 11;
  dst[i] = f2bf(src[(tj * 16 + (ln & 15)) * 128 + kb * 32 + (ln >> 4) * 8 + e]);
}

__global__ __launch_bounds__(256) void pack_kernel(
    const float* __restrict__ x,
    const float* __restrict__ Wih1, const float* __restrict__ Whh1,
    const float* __restrict__ bih1, const float* __restrict__ bhh1,
    const float* __restrict__ Wself1, const float* __restrict__ Wneigh1,
    const float* __restrict__ Wih2, const float* __restrict__ Whh2,
    const float* __restrict__ bih2, const float* __restrict__ bhh2,
    const float* __restrict__ Wself2, const float* __restrict__ Wneigh2,
    char* __restrict__ ws)
{
  int i = blockIdx.x * 256 + threadIdx.x;
  if (i < 2560000) { ((u16*)(ws + OFF_X16))[i] = f2bf(x[i]); return; }
  i -= 2560000;
  if (i < 65536) { pack512((u16*)(ws + OFF_WIH1P), Wih1, i); return; }
  i -= 65536;
  if (i < 65536) { pack512((u16*)(ws + OFF_WHH1P), Whh1, i); return; }
  i -= 65536;
  if (i < 65536) { pack512((u16*)(ws + OFF_WIH2P), Wih2, i); return; }
  i -= 65536;
  if (i < 65536) { pack512((u16*)(ws + OFF_WHH2P), Whh2, i); return; }
  i -= 65536;
  if (i < 16384) { pack128((u16*)(ws + OFF_WS1P), Wself1, i); return; }
  i -= 16384;
  if (i < 16384) { pack128((u16*)(ws + OFF_WN1P), Wneigh1, i); return; }
  i -= 16384;
  if (i < 128) { ((u16*)(ws + OFF_WS2B))[i] = f2bf(Wself2[i]); return; }
  i -= 128;
  if (i < 128) { ((u16*)(ws + OFF_WN2B))[i] = f2bf(Wneigh2[i]); return; }
  i -= 128;
  if (i < 512) { ((float*)(ws + OFF_B1))[i] = (bih1[i] + bhh1[i]) * gate_scale(i); return; }
  i -= 512;
  if (i < 512) { ((float*)(ws + OFF_B2))[i] = (bih2[i] + bhh2[i]) * gate_scale(i); }
}

// Xpre[n, 0:512] = inp[n] @ W^T + bias   (W fragment-packed, bias prescaled fp32)
// gates^T layout: per wave 16 nodes, 32 j-tiles. fp32 output.
__global__ __launch_bounds__(256) void xpre_kernel(
    const u16* __restrict__ inp,    // [NN,128] bf16
    const frag8* __restrict__ Wp,   // 8192 frags
    const float* __restrict__ bias, // [512] fp32 prescaled
    float* __restrict__ outp)       // [NN,512] fp32
{
  const int lane = threadIdx.x & 63, wave = threadIdx.x >> 6;
  const int m = lane & 15, quad = lane >> 4;
  const int node_base = (blockIdx.x * 4 + wave) * 16;
  if (node_base >= NN) return;
  const int row = node_base + m;
  frag8 bfr[4];
#pragma unroll
  for (int kb = 0; kb < 4; ++kb)
    bfr[kb] = *(const frag8*)(inp + (size_t)row * 128 + kb * 32 + quad * 8);
#pragma unroll
  for (int tj = 0; tj < 32; ++tj) {
    float4 bv = *(const float4*)(bias + tj * 16 + quad * 4);
    facc4 acc = {bv.x, bv.y, bv.z, bv.w};
#pragma unroll
    for (int kb = 0; kb < 4; ++kb)
      acc = mfma16(Wp[(tj * 4 + kb) * 64 + lane], bfr[kb], acc);
    float4 st = {acc[0], acc[1], acc[2], acc[3]};
    *(float4*)(outp + (size_t)row * 512 + tj * 16 + quad * 4) = st;
  }
}

// 16-step LSTM over gathered neighbor sequences; final h -> hN (bf16).
__global__ __launch_bounds__(320) void lstm_kernel(
    const float* __restrict__ Xpre, // [NN,512] fp32, prescaled, bias folded
    const frag8* __restrict__ Wp,   // packed Whh, 8192 frags (128 KB)
    const int* __restrict__ nbr,    // [NN,16]
    u16* __restrict__ hN)           // [NN,128] bf16
{
  __shared__ frag8 Wlds[8192];                       // 131072 B
  __shared__ __align__(16) u16 h_lds[5][16 * 136];   // 21760 B (pad 136: 2-way banks)
  const int tid = threadIdx.x;
  const int lane = tid & 63, wave = tid >> 6;
  const int m = lane & 15, quad = lane >> 4;

  for (int i = tid; i < 8192; i += 320) Wlds[i] = Wp[i];
  u16* hl = h_lds[wave];
  for (int i = lane; i < 16 * 136; i += 64) hl[i] = 0;
  __syncthreads();

  const int node_base = (blockIdx.x * 5 + wave) * 16;   // 250*5*16 == 20000 exact
  // lane holds nbr[node_base + m][quad*4 + s], s=0..3
  int4 idx4 = *(const int4*)(nbr + (size_t)(node_base + m) * 16 + quad * 4);

  facc4 c[8];
#pragma unroll
  for (int kt = 0; kt < 8; ++kt) c[kt] = (facc4){0.f, 0.f, 0.f, 0.f};

#pragma unroll 1
  for (int t = 0; t < 16; ++t) {
    const int tq = t >> 2, ts = t & 3;
    int sel = (ts == 0) ? idx4.x : (ts == 1) ? idx4.y : (ts == 2) ? idx4.z : idx4.w;
    int idx = __shfl(sel, m + (tq << 4), 64);           // neighbor of node m at step t
    const float* xrow = Xpre + (size_t)idx * 512;

    frag8 bfr[4];                                       // B = h (prev step) from LDS
#pragma unroll
    for (int kb = 0; kb < 4; ++kb)
      bfr[kb] = *(const frag8*)(hl + m * 136 + kb * 32 + quad * 8);

#pragma unroll
    for (int kt = 0; kt < 8; ++kt) {
      facc4 ai = *(const facc4*)(xrow + (0 * 128 + kt * 16) + quad * 4);
      facc4 af = *(const facc4*)(xrow + (1 * 128 + kt * 16) + quad * 4);
      facc4 ag = *(const facc4*)(xrow + (2 * 128 + kt * 16) + quad * 4);
      facc4 ao = *(const facc4*)(xrow + (3 * 128 + kt * 16) + quad * 4);
#pragma unroll
      for (int kb = 0; kb < 4; ++kb) {
        ai = mfma16(Wlds[((0 * 8 + kt) * 4 + kb) * 64 + lane], bfr[kb], ai);
        af = mfma16(Wlds[((1 * 8 + kt) * 4 + kb) * 64 + lane], bfr[kb], af);
        ag = mfma16(Wlds[((2 * 8 + kt) * 4 + kb) * 64 + lane], bfr[kb], ag);
        ao = mfma16(Wlds[((3 * 8 + kt) * 4 + kb) * 64 + lane], bfr[kb], ao);
      }
      facc4 hv;
#pragma unroll
      for (int r = 0; r < 4; ++r) {
        float si = sigm_ps(ai[r]);
        float sf = sigm_ps(af[r]);
        float tg = tanh_ps(ag[r]);
        float cn = sf * c[kt][r] + si * tg;
        c[kt][r] = cn;
        float so = sigm_ps(ao[r]);
        hv[r] = so * tanh_ps((2.f * L2E) * cn);
      }
      uint2 hp;
      hp.x = (unsigned)f2bf(hv[0]) | ((unsigned)f2bf(hv[1]) << 16);
      hp.y = (unsigned)f2bf(hv[2]) | ((unsigned)f2bf(hv[3]) << 16);
      *(uint2*)(hl + m * 136 + kt * 16 + quad * 4) = hp;
    }
  }
#pragma unroll
  for (int kt = 0; kt < 8; ++kt) {
    uint2 hp = *(const uint2*)(hl + m * 136 + kt * 16 + quad * 4);
    *(uint2*)(hN + (size_t)(node_base + m) * 128 + kt * 16 + quad * 4) = hp;
  }
}

// h1 = relu(x@Wself^T + hN@Wneigh^T + bneigh), bf16 out. 8 j-tiles.
__global__ __launch_bounds__(256) void out1_kernel(
    const u16* __restrict__ x16, const u16* __restrict__ hN,
    const frag8* __restrict__ Wsp, const frag8* __restrict__ Wnp,
    const float* __restrict__ bneigh, u16* __restrict__ h1)
{
  const int lane = threadIdx.x & 63, wave = threadIdx.x >> 6;
  const int m = lane & 15, quad = lane >> 4;
  const int node_base = (blockIdx.x * 4 + wave) * 16;
  if (node_base >= NN) return;
  const int row = node_base + m;
  frag8 bx[4], bh[4];
#pragma unroll
  for (int kb = 0; kb < 4; ++kb) {
    bx[kb] = *(const frag8*)(x16 + (size_t)row * 128 + kb * 32 + quad * 8);
    bh[kb] = *(const frag8*)(hN + (size_t)row * 128 + kb * 32 + quad * 8);
  }
#pragma unroll
  for (int tj = 0; tj < 8; ++tj) {
    float4 bv = *(const float4*)(bneigh + tj * 16 + quad * 4);
    facc4 acc = {bv.x, bv.y, bv.z, bv.w};
#pragma unroll
    for (int kb = 0; kb < 4; ++kb) {
      acc = mfma16(Wsp[(tj * 4 + kb) * 64 + lane], bx[kb], acc);
      acc = mfma16(Wnp[(tj * 4 + kb) * 64 + lane], bh[kb], acc);
    }
#pragma unroll
    for (int r = 0; r < 4; ++r) acc[r] = fmaxf(acc[r], 0.f);
    uint2 st;
    st.x = (unsigned)f2bf(acc[0]) | ((unsigned)f2bf(acc[1]) << 16);
    st.y = (unsigned)f2bf(acc[2]) | ((unsigned)f2bf(acc[3]) << 16);
    *(uint2*)(h1 + (size_t)row * 128 + tj * 16 + quad * 4) = st;
  }
}

__device__ __forceinline__ float dot2(unsigned a, unsigned b) {
  return bflo(a) * bflo(b) + bfhi(a) * bfhi(b);
}

// out[n] = sigmoid(h1[n].Wself2 + hN2[n].Wneigh2 + b), fp32 out
__global__ __launch_bounds__(256) void out2_kernel(
    const u16* __restrict__ h1, const u16* __restrict__ hN2,
    const u16* __restrict__ ws2, const u16* __restrict__ wn2,
    const float* __restrict__ b2, float* __restrict__ outp)
{
  int n = blockIdx.x * 256 + threadIdx.x;
  if (n >= NN) return;
  const uint4* r1 = (const uint4*)(h1 + (size_t)n * 128);
  const uint4* r2 = (const uint4*)(hN2 + (size_t)n * 128);
  const uint4* w1 = (const uint4*)ws2;
  const uint4* w2 = (const uint4*)wn2;
  float acc = b2[0];
#pragma unroll
  for (int q = 0; q < 16; ++q) {   // R1 fix: 16 uint4 = 128 features (was 8)
    uint4 a = r1[q], w = w1[q];
    acc += dot2(a.x, w.x) + dot2(a.y, w.y) + dot2(a.z, w.z) + dot2(a.w, w.w);
    uint4 c = r2[q], v = w2[q];
    acc += dot2(c.x, v.x) + dot2(c.y, v.y) + dot2(c.z, v.z) + dot2(c.w, v.w);
  }
  outp[n] = __builtin_amdgcn_rcpf(1.f + __builtin_amdgcn_exp2f(-acc * L2E));
}

extern "C" void kernel_launch(void* const* d_in, const int* in_sizes, int n_in,
                              void* d_out, int out_size, void* d_ws, size_t ws_size,
                              hipStream_t stream) {
  const float* x       = (const float*)d_in[0];
  const int*   nbr     = (const int*)d_in[1];
  const float* Wih1    = (const float*)d_in[2];
  const float* Whh1    = (const float*)d_in[3];
  const float* bih1    = (const float*)d_in[4];
  const float* bhh1    = (const float*)d_in[5];
  const float* Wself1  = (const float*)d_in[6];
  const float* Wneigh1 = (const float*)d_in[7];
  const float* bneigh1 = (const float*)d_in[8];
  const float* Wih2    = (const float*)d_in[9];
  const float* Whh2    = (const float*)d_in[10];
  const float* bih2    = (const float*)d_in[11];
  const float* bhh2    = (const float*)d_in[12];
  const float* Wself2  = (const float*)d_in[13];
  const float* Wneigh2 = (const float*)d_in[14];
  const float* bneigh2 = (const float*)d_in[15];

  char* ws = (char*)d_ws;
  u16*   x16   = (u16*)(ws + OFF_X16);
  u16*   h1    = (u16*)(ws + OFF_H1);
  u16*   hN    = (u16*)(ws + OFF_HN);
  float* Xpre  = (float*)(ws + OFF_XPRE);
  frag8* Wih1p = (frag8*)(ws + OFF_WIH1P);
  frag8* Whh1p = (frag8*)(ws + OFF_WHH1P);
  frag8* Wih2p = (frag8*)(ws + OFF_WIH2P);
  frag8* Whh2p = (frag8*)(ws + OFF_WHH2P);
  frag8* Ws1p  = (frag8*)(ws + OFF_WS1P);
  frag8* Wn1p  = (frag8*)(ws + OFF_WN1P);
  u16*   Ws2b  = (u16*)(ws + OFF_WS2B);
  u16*   Wn2b  = (u16*)(ws + OFF_WN2B);
  float* b1    = (float*)(ws + OFF_B1);
  float* b2    = (float*)(ws + OFF_B2);

  pack_kernel<<<11157, 256, 0, stream>>>(x, Wih1, Whh1, bih1, bhh1, Wself1,
                                         Wneigh1, Wih2, Whh2, bih2, bhh2,
                                         Wself2, Wneigh2, ws);
  // layer 1
  xpre_kernel<<<313, 256, 0, stream>>>(x16, Wih1p, b1, Xpre);
  lstm_kernel<<<250, 320, 0, stream>>>(Xpre, Whh1p, nbr, hN);
  out1_kernel<<<313, 256, 0, stream>>>(x16, hN, Ws1p, Wn1p, bneigh1, h1);
  // layer 2
  xpre_kernel<<<313, 256, 0, stream>>>(h1, Wih2p, b2, Xpre);
  lstm_kernel<<<250, 320, 0, stream>>>(Xpre, Whh2p, nbr, hN);
  out2_kernel<<<79, 256, 0, stream>>>(h1, hN, Ws2b, Wn2b, bneigh2, (float*)d_out);
}